// Round 1
// baseline (173.110 us; speedup 1.0000x reference)
//
#include <hip/hip_runtime.h>
#include <hip/hip_bf16.h>

// Cylindrical pooling: for each box, select first S in-radius points (ascending
// index), append box velocity, zero remaining slots.
//
// Exact f32 semantics: distance = __fsqrt_rn(__fadd_rn(dx*dx, dy*dy)) with
// _rn intrinsics to forbid FMA contraction (selection boundaries must match
// the numpy/JAX reference bit-exactly).

__device__ __forceinline__ float box_radius(const float* __restrict__ b) {
    float hx = __fmul_rn(b[3], 0.5f);
    float hy = __fmul_rn(b[4], 0.5f);
    float nrm = __fsqrt_rn(__fadd_rn(__fmul_rn(hx, hx), __fmul_rn(hy, hy)));
    return __fmul_rn(nrm, 1.1f);   // GAMMA
}

__device__ __forceinline__ bool in_radius(float bx, float by, float r,
                                          float px, float py) {
    float dx = __fsub_rn(bx, px);
    float dy = __fsub_rn(by, py);
    float dis = __fsqrt_rn(__fadd_rn(__fmul_rn(dx, dx), __fmul_rn(dy, dy)));
    return dis <= r;
}

// ---------------- Kernel 1: per-(box, 64-point-group) counts ----------------
// Grid: ceil(N/256) blocks x 256 threads. Block covers 256 points (4 groups).
// Each thread holds one point; loop over boxes staged in LDS.
__global__ __launch_bounds__(256) void count_kernel(
    const float* __restrict__ pts, const float* __restrict__ boxes,
    int* __restrict__ counts, int N, int M, int ngrp) {
    extern __shared__ float smem[];
    float* s_bx = smem;
    float* s_by = smem + M;
    float* s_r  = smem + 2 * M;

    int tid = threadIdx.x;
    int lane = tid & 63;
    int wid = tid >> 6;

    for (int m = tid; m < M; m += 256) {
        const float* b = boxes + m * 9;
        s_bx[m] = b[0];
        s_by[m] = b[1];
        s_r[m]  = box_radius(b);
    }
    __syncthreads();

    int p = blockIdx.x * 256 + tid;
    bool valid = p < N;
    float px = 0.f, py = 0.f;
    if (valid) {
        px = pts[p * 5 + 0];
        py = pts[p * 5 + 1];
    }

    int g = blockIdx.x * 4 + wid;  // 64-point group id
    for (int m = 0; m < M; ++m) {
        bool in = valid && in_radius(s_bx[m], s_by[m], s_r[m], px, py);
        unsigned long long bal = __ballot(in);
        if (lane == 0) counts[m * ngrp + g] = __popcll(bal);
    }
}

// ---------------- Kernel 2: per-box scan + ordered emission ----------------
// Grid: M blocks x 256 threads. Block-wide exclusive scan of group counts,
// then each wave independently processes groups whose prefix < S.
__global__ __launch_bounds__(256) void emit_kernel(
    const float* __restrict__ pts, const float* __restrict__ boxes,
    const int* __restrict__ counts, float* __restrict__ out,
    int N, int M, int S, int ngrp) {
    extern __shared__ int s_pref[];       // ngrp + 1 entries
    __shared__ int s_wsum[4];

    int m = blockIdx.x;
    int tid = threadIdx.x;
    int lane = tid & 63;
    int wid = tid >> 6;

    const float* b = boxes + m * 9;
    float bx = b[0], by = b[1];
    float r = box_radius(b);
    float vx = b[7], vy = b[8];

    const int* my_counts = counts + (size_t)m * ngrp;
    const int gpt = (ngrp + 255) >> 8;    // groups per thread
    const int g0 = tid * gpt;

    int tsum = 0;
    for (int i = 0; i < gpt; ++i) {
        int g = g0 + i;
        if (g < ngrp) tsum += my_counts[g];
    }

    // wave-inclusive scan of tsum
    int v = tsum;
    #pragma unroll
    for (int d = 1; d < 64; d <<= 1) {
        int u = __shfl_up(v, d, 64);
        if (lane >= d) v += u;
    }
    if (lane == 63) s_wsum[wid] = v;
    __syncthreads();
    int woff = 0;
    for (int w = 0; w < wid; ++w) woff += s_wsum[w];
    int running = woff + (v - tsum);      // exclusive thread base

    for (int i = 0; i < gpt; ++i) {
        int g = g0 + i;
        if (g < ngrp) {
            s_pref[g] = running;
            running += my_counts[g];
        }
    }
    if (tid == 255) s_pref[ngrp] = running;  // total (thread 255 ends at total)
    __syncthreads();

    // emission: one wave per group, independent iterations (pipelineable)
    for (int g = wid; g < ngrp; g += 4) {
        int base = s_pref[g];
        if (base >= S || s_pref[g + 1] == base) continue;
        int p = g * 64 + lane;
        bool in = false;
        if (p < N) {
            float px = pts[p * 5 + 0];
            float py = pts[p * 5 + 1];
            in = in_radius(bx, by, r, px, py);
        }
        unsigned long long bal = __ballot(in);
        int rank = __popcll(bal & ((1ull << lane) - 1ull));
        int pos = base + rank;
        if (in && pos < S) {
            float* o = out + ((size_t)m * S + pos) * 7;
            const float* pp = pts + (size_t)p * 5;
            o[0] = pp[0]; o[1] = pp[1]; o[2] = pp[2];
            o[3] = pp[3]; o[4] = pp[4];
            o[5] = vx;    o[6] = vy;
        }
    }

    // zero-fill tail slots [min(total,S), S)
    int total = s_pref[ngrp];
    int cnt = total < S ? total : S;
    size_t outbase = (size_t)m * S * 7;
    for (int i = cnt * 7 + tid; i < S * 7; i += 256) out[outbase + i] = 0.0f;
}

// ---------------- Fallback: serialized scan (if ws too small) ----------------
__global__ __launch_bounds__(256) void simple_kernel(
    const float* __restrict__ pts, const float* __restrict__ boxes,
    float* __restrict__ out, int N, int M, int S) {
    __shared__ int s_wc[4];
    int m = blockIdx.x;
    int tid = threadIdx.x;
    int lane = tid & 63;
    int wid = tid >> 6;

    const float* b = boxes + m * 9;
    float bx = b[0], by = b[1];
    float r = box_radius(b);
    float vx = b[7], vy = b[8];

    int base = 0;
    for (int start = 0; start < N && base < S; start += 256) {
        int p = start + tid;
        bool in = false;
        if (p < N) {
            float px = pts[p * 5 + 0];
            float py = pts[p * 5 + 1];
            in = in_radius(bx, by, r, px, py);
        }
        unsigned long long bal = __ballot(in);
        if (lane == 0) s_wc[wid] = __popcll(bal);
        __syncthreads();
        int off = 0;
        for (int w = 0; w < wid; ++w) off += s_wc[w];
        int pos = base + off + __popcll(bal & ((1ull << lane) - 1ull));
        if (in && pos < S) {
            float* o = out + ((size_t)m * S + pos) * 7;
            const float* pp = pts + (size_t)p * 5;
            o[0] = pp[0]; o[1] = pp[1]; o[2] = pp[2];
            o[3] = pp[3]; o[4] = pp[4];
            o[5] = vx;    o[6] = vy;
        }
        base += s_wc[0] + s_wc[1] + s_wc[2] + s_wc[3];
        __syncthreads();
    }

    int cnt = base < S ? base : S;
    size_t outbase = (size_t)m * S * 7;
    for (int i = cnt * 7 + tid; i < S * 7; i += 256) out[outbase + i] = 0.0f;
}

extern "C" void kernel_launch(void* const* d_in, const int* in_sizes, int n_in,
                              void* d_out, int out_size, void* d_ws, size_t ws_size,
                              hipStream_t stream) {
    const float* pts = (const float*)d_in[0];
    const float* boxes = (const float*)d_in[1];
    float* out = (float*)d_out;

    int N = in_sizes[0] / 5;
    int M = in_sizes[1] / 9;
    int S = out_size / (M * 7);
    int ngrp = (N + 63) / 64;

    size_t need = (size_t)M * ngrp * sizeof(int);
    if (ws_size >= need) {
        int* counts = (int*)d_ws;
        int nblk = (N + 255) / 256;
        count_kernel<<<nblk, 256, (size_t)3 * M * sizeof(float), stream>>>(
            pts, boxes, counts, N, M, ngrp);
        emit_kernel<<<M, 256, (size_t)(ngrp + 1) * sizeof(int), stream>>>(
            pts, boxes, counts, out, N, M, S, ngrp);
    } else {
        simple_kernel<<<M, 256, 0, stream>>>(pts, boxes, out, N, M, S);
    }
}

// Round 2
// 69.870 us; speedup vs baseline: 2.4776x; 2.4776x over previous
//
#include <hip/hip_runtime.h>
#include <hip/hip_bf16.h>

// Cylindrical pooling: for each box, select first S in-radius points (ascending
// index), append box velocity, zero remaining slots.
//
// Exact f32 semantics: distance = __fsqrt_rn(__fadd_rn(dx*dx, dy*dy)) with
// _rn intrinsics to forbid FMA contraction (selection boundaries must match
// the numpy/JAX reference bit-exactly).

__device__ __forceinline__ float box_radius(const float* __restrict__ b) {
    float hx = __fmul_rn(b[3], 0.5f);
    float hy = __fmul_rn(b[4], 0.5f);
    float nrm = __fsqrt_rn(__fadd_rn(__fmul_rn(hx, hx), __fmul_rn(hy, hy)));
    return __fmul_rn(nrm, 1.1f);   // GAMMA
}

__device__ __forceinline__ bool in_radius(float bx, float by, float r,
                                          float px, float py) {
    float dx = __fsub_rn(bx, px);
    float dy = __fsub_rn(by, py);
    float dis = __fsqrt_rn(__fadd_rn(__fmul_rn(dx, dx), __fmul_rn(dy, dy)));
    return dis <= r;
}

// ---------------- Kernel 0: per-box (bx, by, radius) table ----------------
__global__ __launch_bounds__(256) void prep_kernel(
    const float* __restrict__ boxes, float4* __restrict__ bprep, int M) {
    int m = blockIdx.x * blockDim.x + threadIdx.x;
    if (m < M) {
        const float* b = boxes + (size_t)m * 9;
        bprep[m] = make_float4(b[0], b[1], box_radius(b), 0.0f);
    }
}

// ---------------- Kernel 1: per-(box, 64-point-group) counts ----------------
// Grid: ceil(N/256) x 256 threads. Each thread holds one point; loop over
// boxes via wave-uniform float4 loads (s_load), unrolled so independent
// scalar-load->compute chains pipeline.
__global__ __launch_bounds__(256) void count_kernel(
    const float* __restrict__ pts, const float4* __restrict__ bprep,
    int* __restrict__ counts, int N, int M, int ngrp) {
    int tid = threadIdx.x;
    int lane = tid & 63;
    int wid = tid >> 6;

    int p = blockIdx.x * 256 + tid;
    bool valid = p < N;
    float px = 0.f, py = 0.f;
    if (valid) {
        px = pts[(size_t)p * 5 + 0];
        py = pts[(size_t)p * 5 + 1];
    }

    int g = blockIdx.x * 4 + wid;  // 64-point group id
    bool gok = g < ngrp;

    #pragma unroll 4
    for (int m = 0; m < M; ++m) {
        float4 bb = bprep[m];      // wave-uniform -> scalar load
        bool in = valid && in_radius(bb.x, bb.y, bb.z, px, py);
        unsigned long long bal = __ballot(in);
        if (lane == 0 && gok) counts[(size_t)m * ngrp + g] = __popcll(bal);
    }
}

// ---------------- Kernel 2: per-box scan + worklist + emission ----------------
// Grid: M blocks x 1024 threads (16 waves). Block scan of group counts held in
// registers; threads append qualifying groups (count>0 && base<S, provably <=S
// of them) to an LDS worklist; waves then process only the worklist.
__global__ __launch_bounds__(1024) void emit_kernel(
    const float* __restrict__ pts, const float* __restrict__ boxes,
    const float4* __restrict__ bprep,
    const int* __restrict__ counts, float* __restrict__ out,
    int N, int M, int S, int ngrp) {
    extern __shared__ int s_work[];        // S + 64 entries
    __shared__ int s_wsum[16];
    __shared__ int s_nwork;

    int m = blockIdx.x;
    int tid = threadIdx.x;
    int lane = tid & 63;
    int wid = tid >> 6;
    int nw = blockDim.x >> 6;              // 16

    if (tid == 0) s_nwork = 0;

    float4 bb = bprep[m];
    float bx = bb.x, by = bb.y, r = bb.z;
    float vx = boxes[(size_t)m * 9 + 7];
    float vy = boxes[(size_t)m * 9 + 8];

    const int* my_counts = counts + (size_t)m * ngrp;
    int gpt = (ngrp + blockDim.x - 1) / blockDim.x;   // 4 at N=262144
    int g0 = tid * gpt;

    int c[8];                               // gpt <= 8 guaranteed by launcher
    int tsum = 0;
    if (gpt == 4 && (g0 & 3) == 0 && g0 + 3 < ngrp) {
        int4 v4 = *reinterpret_cast<const int4*>(my_counts + g0);
        c[0] = v4.x; c[1] = v4.y; c[2] = v4.z; c[3] = v4.w;
        tsum = c[0] + c[1] + c[2] + c[3];
    } else {
        #pragma unroll
        for (int i = 0; i < 8; ++i) {
            int g = g0 + i;
            c[i] = (i < gpt && g < ngrp) ? my_counts[g] : 0;
            tsum += c[i];
        }
    }

    // wave-inclusive scan of tsum
    int v = tsum;
    #pragma unroll
    for (int d = 1; d < 64; d <<= 1) {
        int u = __shfl_up(v, d, 64);
        if (lane >= d) v += u;
    }
    if (lane == 63) s_wsum[wid] = v;
    __syncthreads();

    int woff = 0, total = 0;
    for (int w = 0; w < nw; ++w) {
        int s = s_wsum[w];
        total += s;
        if (w < wid) woff += s;
    }
    int base = woff + (v - tsum);          // exclusive prefix of thread's first group

    // worklist build: order within list is irrelevant (positions precomputed)
    for (int i = 0; i < gpt; ++i) {
        int cnt = c[i];
        if (cnt > 0 && base < S) {
            int slot = atomicAdd(&s_nwork, 1);
            s_work[slot] = (base << 16) | (g0 + i);
        }
        base += cnt;
    }
    __syncthreads();
    int nwork = s_nwork;

    // emission: one wave per worklist entry
    for (int i = wid; i < nwork; i += nw) {
        int e = s_work[i];
        int g = e & 0xffff;
        int gbase = e >> 16;
        int p = g * 64 + lane;
        bool in = false;
        float px = 0.f, py = 0.f;
        if (p < N) {
            px = pts[(size_t)p * 5 + 0];
            py = pts[(size_t)p * 5 + 1];
            in = in_radius(bx, by, r, px, py);
        }
        unsigned long long bal = __ballot(in);
        int rank = __popcll(bal & ((1ull << lane) - 1ull));
        int pos = gbase + rank;
        if (in && pos < S) {
            float* o = out + ((size_t)m * S + pos) * 7;
            const float* pp = pts + (size_t)p * 5;
            o[0] = px;    o[1] = py;    o[2] = pp[2];
            o[3] = pp[3]; o[4] = pp[4];
            o[5] = vx;    o[6] = vy;
        }
    }

    // zero-fill tail slots [min(total,S), S)
    int cnt = total < S ? total : S;
    size_t outbase = (size_t)m * S * 7;
    for (int i = cnt * 7 + tid; i < S * 7; i += blockDim.x) out[outbase + i] = 0.0f;
}

// ---------------- Fallback: serialized scan (if ws too small) ----------------
__global__ __launch_bounds__(256) void simple_kernel(
    const float* __restrict__ pts, const float* __restrict__ boxes,
    float* __restrict__ out, int N, int M, int S) {
    __shared__ int s_wc[4];
    int m = blockIdx.x;
    int tid = threadIdx.x;
    int lane = tid & 63;
    int wid = tid >> 6;

    const float* b = boxes + (size_t)m * 9;
    float bx = b[0], by = b[1];
    float r = box_radius(b);
    float vx = b[7], vy = b[8];

    int base = 0;
    for (int start = 0; start < N && base < S; start += 256) {
        int p = start + tid;
        bool in = false;
        if (p < N) {
            float px = pts[(size_t)p * 5 + 0];
            float py = pts[(size_t)p * 5 + 1];
            in = in_radius(bx, by, r, px, py);
        }
        unsigned long long bal = __ballot(in);
        if (lane == 0) s_wc[wid] = __popcll(bal);
        __syncthreads();
        int off = 0;
        for (int w = 0; w < wid; ++w) off += s_wc[w];
        int pos = base + off + __popcll(bal & ((1ull << lane) - 1ull));
        if (in && pos < S) {
            float* o = out + ((size_t)m * S + pos) * 7;
            const float* pp = pts + (size_t)p * 5;
            o[0] = pp[0]; o[1] = pp[1]; o[2] = pp[2];
            o[3] = pp[3]; o[4] = pp[4];
            o[5] = vx;    o[6] = vy;
        }
        base += s_wc[0] + s_wc[1] + s_wc[2] + s_wc[3];
        __syncthreads();
    }

    int cnt = base < S ? base : S;
    size_t outbase = (size_t)m * S * 7;
    for (int i = cnt * 7 + tid; i < S * 7; i += 256) out[outbase + i] = 0.0f;
}

extern "C" void kernel_launch(void* const* d_in, const int* in_sizes, int n_in,
                              void* d_out, int out_size, void* d_ws, size_t ws_size,
                              hipStream_t stream) {
    const float* pts = (const float*)d_in[0];
    const float* boxes = (const float*)d_in[1];
    float* out = (float*)d_out;

    int N = in_sizes[0] / 5;
    int M = in_sizes[1] / 9;
    int S = out_size / (M * 7);
    int ngrp = (N + 63) / 64;

    size_t counts_bytes = (size_t)M * ngrp * sizeof(int);
    size_t need = counts_bytes + (size_t)M * sizeof(float4);
    int gpt = (ngrp + 1023) / 1024;

    if (ws_size >= need && gpt <= 8 && S < 32768 && ngrp < 65536) {
        int* counts = (int*)d_ws;
        float4* bprep = (float4*)((char*)d_ws + counts_bytes);
        prep_kernel<<<(M + 255) / 256, 256, 0, stream>>>(boxes, bprep, M);
        int nblk = (N + 255) / 256;
        count_kernel<<<nblk, 256, 0, stream>>>(pts, bprep, counts, N, M, ngrp);
        size_t lds = (size_t)(S + 64) * sizeof(int);
        emit_kernel<<<M, 1024, lds, stream>>>(pts, boxes, bprep, counts, out,
                                              N, M, S, ngrp);
    } else {
        simple_kernel<<<M, 256, 0, stream>>>(pts, boxes, out, N, M, S);
    }
}

// Round 3
// 34.573 us; speedup vs baseline: 5.0071x; 2.0210x over previous
//
#include <hip/hip_runtime.h>
#include <hip/hip_bf16.h>
#include <math.h>

// Cylindrical pooling: for each box, select first S in-radius points (ascending
// index), append box velocity, zero remaining slots.
//
// Exact f32 semantics: reference computes dis = sqrt_rn(dx*dx + dy*dy) (no FMA
// contraction) and tests dis <= r. sqrt_rn is monotone, so dis <= r  <=>
// d2 <= T where T = max{x : sqrt_rn(x) <= r}, precomputed per box by a
// nextafter walk. This removes the expensive correctly-rounded sqrt from the
// 67M-pair inner loop while remaining bit-exact.

__device__ __forceinline__ float box_radius(const float* __restrict__ b) {
    float hx = __fmul_rn(b[3], 0.5f);
    float hy = __fmul_rn(b[4], 0.5f);
    float nrm = __fsqrt_rn(__fadd_rn(__fmul_rn(hx, hx), __fmul_rn(hy, hy)));
    return __fmul_rn(nrm, 1.1f);   // GAMMA
}

// largest finite x with __fsqrt_rn(x) <= r  (r >= 0)
__device__ float sqrt_le_threshold(float r) {
    float x = __fmul_rn(r, r);
    // walk up while the next value still satisfies
    #pragma unroll 1
    for (int i = 0; i < 16; ++i) {
        float nx = nextafterf(x, INFINITY);
        if (__fsqrt_rn(nx) <= r) x = nx; else break;
    }
    // walk down if currently violating
    #pragma unroll 1
    for (int i = 0; i < 16; ++i) {
        if (__fsqrt_rn(x) <= r) break;
        x = nextafterf(x, -INFINITY);
    }
    return x;
}

// ---------------- Kernel 0: per-box (bx, by, T) table ----------------
__global__ __launch_bounds__(256) void prep_kernel(
    const float* __restrict__ boxes, float4* __restrict__ bprep, int M) {
    int m = blockIdx.x * blockDim.x + threadIdx.x;
    if (m < M) {
        const float* b = boxes + (size_t)m * 9;
        bprep[m] = make_float4(b[0], b[1], sqrt_le_threshold(box_radius(b)), 0.0f);
    }
}

// ---------------- Kernel 1: per-(box, 64-point-group) counts ----------------
// Each wave holds 256 points (4 per thread, p = pbase + i*64 + lane) so one
// ballot per i gives one group's mask. Boxes split into `msplit` grid chunks
// for occupancy. Lane 0 stores 4 counts as int4.
__global__ __launch_bounds__(256) void count_kernel(
    const float* __restrict__ pts, const float4* __restrict__ bprep,
    int* __restrict__ counts, int N, int M, int ngrp, int ntile, int mchunk) {
    int tid = threadIdx.x;
    int lane = tid & 63;
    int wid = tid >> 6;

    int tile = blockIdx.x % ntile;
    int mc = blockIdx.x / ntile;
    int m0 = mc * mchunk;
    int m1 = m0 + mchunk; if (m1 > M) m1 = M;

    int pbase = tile * 1024 + wid * 256;
    float px[4], py[4];
    #pragma unroll
    for (int i = 0; i < 4; ++i) {
        int p = pbase + i * 64 + lane;
        bool v = p < N;
        px[i] = v ? pts[(size_t)p * 5 + 0] : 3.0e38f;
        py[i] = v ? pts[(size_t)p * 5 + 1] : 3.0e38f;
    }
    int g0 = pbase >> 6;
    if (g0 >= ngrp) return;
    bool vec4 = ((ngrp & 3) == 0) && (g0 + 4 <= ngrp);

    #pragma unroll 2
    for (int m = m0; m < m1; ++m) {
        float4 bb = bprep[m];           // wave-uniform -> s_load
        float bx = bb.x, by = bb.y, T = bb.z;
        int cnt[4];
        #pragma unroll
        for (int i = 0; i < 4; ++i) {
            float dx = __fsub_rn(bx, px[i]);
            float dy = __fsub_rn(by, py[i]);
            float d2 = __fadd_rn(__fmul_rn(dx, dx), __fmul_rn(dy, dy));
            cnt[i] = __popcll(__ballot(d2 <= T));
        }
        if (lane == 0) {
            int* dst = counts + (size_t)m * ngrp + g0;
            if (vec4) {
                *reinterpret_cast<int4*>(dst) = make_int4(cnt[0], cnt[1], cnt[2], cnt[3]);
            } else {
                #pragma unroll
                for (int i = 0; i < 4; ++i)
                    if (g0 + i < ngrp) dst[i] = cnt[i];
            }
        }
    }
}

// ---------------- Kernel 2: per-box scan + worklist + emission ----------------
// Grid: M blocks x 1024 threads (16 waves). Block scan of group counts held in
// registers; threads append qualifying groups (count>0 && base<S, provably <=S
// of them) to an LDS worklist; waves then process only the worklist.
__global__ __launch_bounds__(1024) void emit_kernel(
    const float* __restrict__ pts, const float* __restrict__ boxes,
    const float4* __restrict__ bprep,
    const int* __restrict__ counts, float* __restrict__ out,
    int N, int M, int S, int ngrp) {
    extern __shared__ int s_work[];        // S + 64 entries
    __shared__ int s_wsum[16];
    __shared__ int s_nwork;

    int m = blockIdx.x;
    int tid = threadIdx.x;
    int lane = tid & 63;
    int wid = tid >> 6;
    int nw = blockDim.x >> 6;              // 16

    if (tid == 0) s_nwork = 0;

    float4 bb = bprep[m];
    float bx = bb.x, by = bb.y, T = bb.z;
    float vx = boxes[(size_t)m * 9 + 7];
    float vy = boxes[(size_t)m * 9 + 8];

    const int* my_counts = counts + (size_t)m * ngrp;
    int gpt = (ngrp + blockDim.x - 1) / blockDim.x;   // 4 at N=262144
    int g0 = tid * gpt;

    int c[8];                               // gpt <= 8 guaranteed by launcher
    int tsum = 0;
    if (gpt == 4 && (g0 & 3) == 0 && g0 + 3 < ngrp) {
        int4 v4 = *reinterpret_cast<const int4*>(my_counts + g0);
        c[0] = v4.x; c[1] = v4.y; c[2] = v4.z; c[3] = v4.w;
        tsum = c[0] + c[1] + c[2] + c[3];
    } else {
        #pragma unroll
        for (int i = 0; i < 8; ++i) {
            int g = g0 + i;
            c[i] = (i < gpt && g < ngrp) ? my_counts[g] : 0;
            tsum += c[i];
        }
    }

    // wave-inclusive scan of tsum
    int v = tsum;
    #pragma unroll
    for (int d = 1; d < 64; d <<= 1) {
        int u = __shfl_up(v, d, 64);
        if (lane >= d) v += u;
    }
    if (lane == 63) s_wsum[wid] = v;
    __syncthreads();

    int woff = 0, total = 0;
    for (int w = 0; w < nw; ++w) {
        int s = s_wsum[w];
        total += s;
        if (w < wid) woff += s;
    }
    int base = woff + (v - tsum);          // exclusive prefix of thread's first group

    // worklist build: order within list is irrelevant (positions precomputed)
    for (int i = 0; i < gpt; ++i) {
        int cnt = c[i];
        if (cnt > 0 && base < S) {
            int slot = atomicAdd(&s_nwork, 1);
            s_work[slot] = (base << 16) | (g0 + i);
        }
        base += cnt;
    }
    __syncthreads();
    int nwork = s_nwork;

    // emission: one wave per worklist entry
    for (int i = wid; i < nwork; i += nw) {
        int e = s_work[i];
        int g = e & 0xffff;
        int gbase = e >> 16;
        int p = g * 64 + lane;
        bool in = false;
        float px = 0.f, py = 0.f;
        if (p < N) {
            px = pts[(size_t)p * 5 + 0];
            py = pts[(size_t)p * 5 + 1];
            float dx = __fsub_rn(bx, px);
            float dy = __fsub_rn(by, py);
            float d2 = __fadd_rn(__fmul_rn(dx, dx), __fmul_rn(dy, dy));
            in = d2 <= T;
        }
        unsigned long long bal = __ballot(in);
        int rank = __popcll(bal & ((1ull << lane) - 1ull));
        int pos = gbase + rank;
        if (in && pos < S) {
            float* o = out + ((size_t)m * S + pos) * 7;
            const float* pp = pts + (size_t)p * 5;
            o[0] = px;    o[1] = py;    o[2] = pp[2];
            o[3] = pp[3]; o[4] = pp[4];
            o[5] = vx;    o[6] = vy;
        }
    }

    // zero-fill tail slots [min(total,S), S)
    int cnt = total < S ? total : S;
    size_t outbase = (size_t)m * S * 7;
    for (int i = cnt * 7 + tid; i < S * 7; i += blockDim.x) out[outbase + i] = 0.0f;
}

// ---------------- Fallback: serialized scan (if ws too small) ----------------
__device__ __forceinline__ bool in_radius_sqrt(float bx, float by, float r,
                                               float px, float py) {
    float dx = __fsub_rn(bx, px);
    float dy = __fsub_rn(by, py);
    float dis = __fsqrt_rn(__fadd_rn(__fmul_rn(dx, dx), __fmul_rn(dy, dy)));
    return dis <= r;
}

__global__ __launch_bounds__(256) void simple_kernel(
    const float* __restrict__ pts, const float* __restrict__ boxes,
    float* __restrict__ out, int N, int M, int S) {
    __shared__ int s_wc[4];
    int m = blockIdx.x;
    int tid = threadIdx.x;
    int lane = tid & 63;
    int wid = tid >> 6;

    const float* b = boxes + (size_t)m * 9;
    float bx = b[0], by = b[1];
    float r = box_radius(b);
    float vx = b[7], vy = b[8];

    int base = 0;
    for (int start = 0; start < N && base < S; start += 256) {
        int p = start + tid;
        bool in = false;
        if (p < N) {
            float px = pts[(size_t)p * 5 + 0];
            float py = pts[(size_t)p * 5 + 1];
            in = in_radius_sqrt(bx, by, r, px, py);
        }
        unsigned long long bal = __ballot(in);
        if (lane == 0) s_wc[wid] = __popcll(bal);
        __syncthreads();
        int off = 0;
        for (int w = 0; w < wid; ++w) off += s_wc[w];
        int pos = base + off + __popcll(bal & ((1ull << lane) - 1ull));
        if (in && pos < S) {
            float* o = out + ((size_t)m * S + pos) * 7;
            const float* pp = pts + (size_t)p * 5;
            o[0] = pp[0]; o[1] = pp[1]; o[2] = pp[2];
            o[3] = pp[3]; o[4] = pp[4];
            o[5] = vx;    o[6] = vy;
        }
        base += s_wc[0] + s_wc[1] + s_wc[2] + s_wc[3];
        __syncthreads();
    }

    int cnt = base < S ? base : S;
    size_t outbase = (size_t)m * S * 7;
    for (int i = cnt * 7 + tid; i < S * 7; i += 256) out[outbase + i] = 0.0f;
}

extern "C" void kernel_launch(void* const* d_in, const int* in_sizes, int n_in,
                              void* d_out, int out_size, void* d_ws, size_t ws_size,
                              hipStream_t stream) {
    const float* pts = (const float*)d_in[0];
    const float* boxes = (const float*)d_in[1];
    float* out = (float*)d_out;

    int N = in_sizes[0] / 5;
    int M = in_sizes[1] / 9;
    int S = out_size / (M * 7);
    int ngrp = (N + 63) / 64;

    size_t counts_bytes = (size_t)M * ngrp * sizeof(int);
    size_t need = counts_bytes + (size_t)M * sizeof(float4);
    int gpt = (ngrp + 1023) / 1024;

    if (ws_size >= need && gpt <= 8 && S < 32768 && ngrp < 65536) {
        int* counts = (int*)d_ws;
        float4* bprep = (float4*)((char*)d_ws + counts_bytes);
        prep_kernel<<<(M + 255) / 256, 256, 0, stream>>>(boxes, bprep, M);

        int ntile = (N + 1023) / 1024;
        // split boxes so grid ~= 2048 blocks (8 blocks/CU, 32 waves/CU)
        int msplit = 2048 / (ntile > 0 ? ntile : 1);
        if (msplit < 1) msplit = 1;
        if (msplit > M) msplit = M;
        int mchunk = (M + msplit - 1) / msplit;
        msplit = (M + mchunk - 1) / mchunk;
        count_kernel<<<ntile * msplit, 256, 0, stream>>>(
            pts, bprep, counts, N, M, ngrp, ntile, mchunk);

        size_t lds = (size_t)(S + 64) * sizeof(int);
        emit_kernel<<<M, 1024, lds, stream>>>(pts, boxes, bprep, counts, out,
                                              N, M, S, ngrp);
    } else {
        simple_kernel<<<M, 256, 0, stream>>>(pts, boxes, out, N, M, S);
    }
}

// Round 4
// 24.586 us; speedup vs baseline: 7.0411x; 1.4062x over previous
//
#include <hip/hip_runtime.h>
#include <hip/hip_bf16.h>
#include <math.h>

// Cylindrical pooling: for each box, select first S in-radius points (ascending
// index), append box velocity, zero remaining slots.
//
// Exact f32 semantics: reference computes dis = sqrt_rn(dx*dx + dy*dy) (no FMA
// contraction) and tests dis <= r. sqrt_rn is monotone, so dis <= r  <=>
// d2 <= T where T = max{x : sqrt_rn(x) <= r} (nextafter walk, exact).
//
// Saturation-adaptive counting: pass A counts the first P0GRP groups (8192
// points) for every box and records satA = #in-radius there. ~93% of boxes
// (gaussian data) already have >= S hits in that prefix; pass B counts the
// remaining groups only for unsaturated boxes. emit scans only the group
// range that can contribute (prefix < S). Distribution only affects speed,
// never correctness.

#define P0GRP 128   // groups in pass A (64 points each)

__device__ __forceinline__ float box_radius(const float* __restrict__ b) {
    float hx = __fmul_rn(b[3], 0.5f);
    float hy = __fmul_rn(b[4], 0.5f);
    float nrm = __fsqrt_rn(__fadd_rn(__fmul_rn(hx, hx), __fmul_rn(hy, hy)));
    return __fmul_rn(nrm, 1.1f);   // GAMMA
}

// largest finite x with __fsqrt_rn(x) <= r  (r >= 0); uniform short walk
__device__ float sqrt_le_threshold(float r) {
    float x = __fmul_rn(r, r);
    #pragma unroll 1
    for (int i = 0; i < 16; ++i) {
        float nx = nextafterf(x, INFINITY);
        if (__fsqrt_rn(nx) <= r) x = nx; else break;
    }
    #pragma unroll 1
    for (int i = 0; i < 16; ++i) {
        if (__fsqrt_rn(x) <= r) break;
        x = nextafterf(x, -INFINITY);
    }
    return x;
}

// ---------------- Kernel A: params + prefix counts + saturation flag --------
// Grid: M blocks x 1024 threads. Block m handles box m: compute (bx,by,T)
// redundantly in every thread (uniform, no sync), count groups [0, ngrpA),
// block-reduce total -> bprep[m] = (bx, by, T, bits(satA)).
__global__ __launch_bounds__(1024) void countA_kernel(
    const float* __restrict__ pts, const float* __restrict__ boxes,
    int* __restrict__ counts, float4* __restrict__ bprep,
    int N, int M, int ngrp, int ngrpA) {
    __shared__ int s_tot[16];
    int m = blockIdx.x;
    int tid = threadIdx.x;
    int lane = tid & 63;
    int wid = tid >> 6;

    const float* b = boxes + (size_t)m * 9;
    float bx = b[0], by = b[1];
    float T = sqrt_le_threshold(box_radius(b));

    int tot = 0;
    #pragma unroll 2
    for (int g = wid; g < ngrpA; g += 16) {
        int p = g * 64 + lane;
        bool v = p < N;
        float px = v ? pts[(size_t)p * 5 + 0] : 3.0e38f;
        float py = v ? pts[(size_t)p * 5 + 1] : 3.0e38f;
        float dx = __fsub_rn(bx, px);
        float dy = __fsub_rn(by, py);
        float d2 = __fadd_rn(__fmul_rn(dx, dx), __fmul_rn(dy, dy));
        int c = __popcll(__ballot(d2 <= T));
        if (lane == 0) counts[(size_t)m * ngrp + g] = c;
        tot += c;
    }
    if (lane == 0) s_tot[wid] = tot;
    __syncthreads();
    if (tid == 0) {
        int total = 0;
        #pragma unroll
        for (int w = 0; w < 16; ++w) total += s_tot[w];
        bprep[m] = make_float4(bx, by, T, __int_as_float(total));
    }
}

// ---------------- Kernel B: remaining counts for unsaturated boxes ----------
// Grid: ntile x msplit blocks, 256 threads. Each wave holds 256 points of
// groups [ngrpA..); per 64-box-chunk, only boxes with satA < S are counted.
__global__ __launch_bounds__(256) void countB_kernel(
    const float* __restrict__ pts, const float4* __restrict__ bprep,
    int* __restrict__ counts, int N, int M, int S, int ngrp, int ngrpA,
    int ntile, int mchunk) {
    __shared__ float4 s_box[64];
    __shared__ unsigned long long s_mask;
    int tid = threadIdx.x;
    int lane = tid & 63;
    int wid = tid >> 6;

    int tile = blockIdx.x % ntile;
    int mc = blockIdx.x / ntile;
    int m0 = mc * mchunk;
    int nmb = M - m0; if (nmb > mchunk) nmb = mchunk;   // mchunk <= 64

    bool act = false;
    if (tid < nmb) {
        float4 bb = bprep[m0 + tid];
        s_box[tid] = bb;
        act = __float_as_int(bb.w) < S;
    }
    unsigned long long bal = __ballot(act);   // wave 0 holds the real mask
    if (tid == 0) s_mask = bal;
    __syncthreads();
    unsigned long long amask = s_mask;
    if (amask == 0) return;                   // block-uniform

    int pbase = ngrpA * 64 + tile * 1024 + wid * 256;
    int g0 = pbase >> 6;
    if (g0 >= ngrp) return;                   // wave-uniform, no syncs below
    bool vec4 = (g0 + 4 <= ngrp);

    float px[4], py[4];
    #pragma unroll
    for (int i = 0; i < 4; ++i) {
        int p = pbase + i * 64 + lane;
        bool v = p < N;
        px[i] = v ? pts[(size_t)p * 5 + 0] : 3.0e38f;
        py[i] = v ? pts[(size_t)p * 5 + 1] : 3.0e38f;
    }

    while (amask) {
        int mm = __builtin_ctzll(amask);
        amask &= amask - 1;
        float4 bb = s_box[mm];
        float bx = bb.x, by = bb.y, T = bb.z;
        int cnt[4];
        #pragma unroll
        for (int i = 0; i < 4; ++i) {
            float dx = __fsub_rn(bx, px[i]);
            float dy = __fsub_rn(by, py[i]);
            float d2 = __fadd_rn(__fmul_rn(dx, dx), __fmul_rn(dy, dy));
            cnt[i] = __popcll(__ballot(d2 <= T));
        }
        if (lane == 0) {
            int* dst = counts + (size_t)(m0 + mm) * ngrp + g0;
            if (vec4) {
                *reinterpret_cast<int4*>(dst) = make_int4(cnt[0], cnt[1], cnt[2], cnt[3]);
            } else {
                #pragma unroll
                for (int i = 0; i < 4; ++i)
                    if (g0 + i < ngrp) dst[i] = cnt[i];
            }
        }
    }
}

// ---------------- Kernel 2: per-box scan + worklist + emission ----------------
// Grid: M blocks x 1024 threads. Scan only ngrp_eff groups (P0GRP if the box
// saturated in pass A), build worklist of groups with count>0 && base<S,
// waves emit worklist entries.
__global__ __launch_bounds__(1024) void emit_kernel(
    const float* __restrict__ pts, const float* __restrict__ boxes,
    const float4* __restrict__ bprep,
    const int* __restrict__ counts, float* __restrict__ out,
    int N, int M, int S, int ngrp, int ngrpA) {
    extern __shared__ int s_work[];        // S + 64 entries
    __shared__ int s_wsum[16];
    __shared__ int s_nwork;

    int m = blockIdx.x;
    int tid = threadIdx.x;
    int lane = tid & 63;
    int wid = tid >> 6;
    int nw = blockDim.x >> 6;              // 16

    if (tid == 0) s_nwork = 0;

    float4 bb = bprep[m];
    float bx = bb.x, by = bb.y, T = bb.z;
    int satA = __float_as_int(bb.w);
    int ngrp_eff = (satA >= S) ? ngrpA : ngrp;
    float vx = boxes[(size_t)m * 9 + 7];
    float vy = boxes[(size_t)m * 9 + 8];

    const int* my_counts = counts + (size_t)m * ngrp;
    int gpt = (ngrp_eff + blockDim.x - 1) / blockDim.x;   // 1 or 4 typically
    int g0 = tid * gpt;

    int c[8];                               // gpt <= 8 guaranteed by launcher
    int tsum = 0;
    if (gpt == 4 && (g0 & 3) == 0 && g0 + 3 < ngrp_eff) {
        int4 v4 = *reinterpret_cast<const int4*>(my_counts + g0);
        c[0] = v4.x; c[1] = v4.y; c[2] = v4.z; c[3] = v4.w;
        tsum = c[0] + c[1] + c[2] + c[3];
    } else {
        #pragma unroll
        for (int i = 0; i < 8; ++i) {
            int g = g0 + i;
            c[i] = (i < gpt && g < ngrp_eff) ? my_counts[g] : 0;
            tsum += c[i];
        }
    }

    // wave-inclusive scan of tsum
    int v = tsum;
    #pragma unroll
    for (int d = 1; d < 64; d <<= 1) {
        int u = __shfl_up(v, d, 64);
        if (lane >= d) v += u;
    }
    if (lane == 63) s_wsum[wid] = v;
    __syncthreads();

    int woff = 0, total = 0;
    for (int w = 0; w < nw; ++w) {
        int s = s_wsum[w];
        total += s;
        if (w < wid) woff += s;
    }
    int base = woff + (v - tsum);          // exclusive prefix of thread's first group

    // worklist build: order within list irrelevant (positions precomputed)
    for (int i = 0; i < gpt; ++i) {
        int cnt = c[i];
        if (cnt > 0 && base < S) {
            int slot = atomicAdd(&s_nwork, 1);
            s_work[slot] = (base << 16) | (g0 + i);
        }
        base += cnt;
    }
    __syncthreads();
    int nwork = s_nwork;

    // emission: one wave per worklist entry
    for (int i = wid; i < nwork; i += nw) {
        int e = s_work[i];
        int g = e & 0xffff;
        int gbase = e >> 16;
        int p = g * 64 + lane;
        bool in = false;
        float px = 0.f, py = 0.f;
        if (p < N) {
            px = pts[(size_t)p * 5 + 0];
            py = pts[(size_t)p * 5 + 1];
            float dx = __fsub_rn(bx, px);
            float dy = __fsub_rn(by, py);
            float d2 = __fadd_rn(__fmul_rn(dx, dx), __fmul_rn(dy, dy));
            in = d2 <= T;
        }
        unsigned long long bal = __ballot(in);
        int rank = __popcll(bal & ((1ull << lane) - 1ull));
        int pos = gbase + rank;
        if (in && pos < S) {
            float* o = out + ((size_t)m * S + pos) * 7;
            const float* pp = pts + (size_t)p * 5;
            o[0] = px;    o[1] = py;    o[2] = pp[2];
            o[3] = pp[3]; o[4] = pp[4];
            o[5] = vx;    o[6] = vy;
        }
    }

    // zero-fill tail slots [min(total,S), S) — empty for saturated boxes
    int cnt = total < S ? total : S;
    size_t outbase = (size_t)m * S * 7;
    for (int i = cnt * 7 + tid; i < S * 7; i += blockDim.x) out[outbase + i] = 0.0f;
}

// ---------------- Fallback: serialized scan (if ws too small) ----------------
__global__ __launch_bounds__(256) void simple_kernel(
    const float* __restrict__ pts, const float* __restrict__ boxes,
    float* __restrict__ out, int N, int M, int S) {
    __shared__ int s_wc[4];
    int m = blockIdx.x;
    int tid = threadIdx.x;
    int lane = tid & 63;
    int wid = tid >> 6;

    const float* b = boxes + (size_t)m * 9;
    float bx = b[0], by = b[1];
    float T = sqrt_le_threshold(box_radius(b));
    float vx = b[7], vy = b[8];

    int base = 0;
    for (int start = 0; start < N && base < S; start += 256) {
        int p = start + tid;
        bool in = false;
        if (p < N) {
            float px = pts[(size_t)p * 5 + 0];
            float py = pts[(size_t)p * 5 + 1];
            float dx = __fsub_rn(bx, px);
            float dy = __fsub_rn(by, py);
            float d2 = __fadd_rn(__fmul_rn(dx, dx), __fmul_rn(dy, dy));
            in = d2 <= T;
        }
        unsigned long long bal = __ballot(in);
        if (lane == 0) s_wc[wid] = __popcll(bal);
        __syncthreads();
        int off = 0;
        for (int w = 0; w < wid; ++w) off += s_wc[w];
        int pos = base + off + __popcll(bal & ((1ull << lane) - 1ull));
        if (in && pos < S) {
            float* o = out + ((size_t)m * S + pos) * 7;
            const float* pp = pts + (size_t)p * 5;
            o[0] = pp[0]; o[1] = pp[1]; o[2] = pp[2];
            o[3] = pp[3]; o[4] = pp[4];
            o[5] = vx;    o[6] = vy;
        }
        base += s_wc[0] + s_wc[1] + s_wc[2] + s_wc[3];
        __syncthreads();
    }

    int cnt = base < S ? base : S;
    size_t outbase = (size_t)m * S * 7;
    for (int i = cnt * 7 + tid; i < S * 7; i += 256) out[outbase + i] = 0.0f;
}

extern "C" void kernel_launch(void* const* d_in, const int* in_sizes, int n_in,
                              void* d_out, int out_size, void* d_ws, size_t ws_size,
                              hipStream_t stream) {
    const float* pts = (const float*)d_in[0];
    const float* boxes = (const float*)d_in[1];
    float* out = (float*)d_out;

    int N = in_sizes[0] / 5;
    int M = in_sizes[1] / 9;
    int S = out_size / (M * 7);
    int ngrp = (N + 63) / 64;
    int ngrpA = ngrp < P0GRP ? ngrp : P0GRP;

    size_t counts_bytes = (size_t)M * ngrp * sizeof(int);
    size_t need = counts_bytes + (size_t)M * sizeof(float4);
    int gpt = (ngrp + 1023) / 1024;

    if (ws_size >= need && gpt <= 8 && S < 32768 && ngrp < 65536 && M <= 65535) {
        int* counts = (int*)d_ws;
        float4* bprep = (float4*)((char*)d_ws + counts_bytes);

        countA_kernel<<<M, 1024, 0, stream>>>(pts, boxes, counts, bprep,
                                              N, M, ngrp, ngrpA);

        if (ngrp > ngrpA) {
            int ntile = (ngrp - ngrpA + 15) / 16;   // tiles of 16 groups (1024 pts)
            int msplit = 2048 / ntile;
            if (msplit < 1) msplit = 1;
            if (msplit > M) msplit = M;
            int mchunk = (M + msplit - 1) / msplit;
            if (mchunk > 64) {                       // LDS/ballot cap
                mchunk = 64;
            }
            msplit = (M + mchunk - 1) / mchunk;
            countB_kernel<<<ntile * msplit, 256, 0, stream>>>(
                pts, bprep, counts, N, M, S, ngrp, ngrpA, ntile, mchunk);
        }

        size_t lds = (size_t)(S + 64) * sizeof(int);
        emit_kernel<<<M, 1024, lds, stream>>>(pts, boxes, bprep, counts, out,
                                              N, M, S, ngrp, ngrpA);
    } else {
        simple_kernel<<<M, 256, 0, stream>>>(pts, boxes, out, N, M, S);
    }
}